// Round 10
// baseline (873.530 us; speedup 1.0000x reference)
//
#include <hip/hip_runtime.h>

#define PI_D 3.14159265358979323846

// ---------------------------------------------------------------------------
// Compile-time twiddle tables: CT[k]=cos(2*pi*k/64), STb[k]=sin(2*pi*k/64).
// ---------------------------------------------------------------------------
namespace {
constexpr float CT[33] = {
  1.0000000000f,  0.9951847267f,  0.9807852804f,  0.9569403357f,
  0.9238795325f,  0.8819212643f,  0.8314696123f,  0.7730104534f,
  0.7071067812f,  0.6343932842f,  0.5555702330f,  0.4713967368f,
  0.3826834324f,  0.2902846773f,  0.1950903220f,  0.0980171403f,
  0.0f,          -0.0980171403f, -0.1950903220f, -0.2902846773f,
 -0.3826834324f, -0.4713967368f, -0.5555702330f, -0.6343932842f,
 -0.7071067812f, -0.7730104534f, -0.8314696123f, -0.8819212643f,
 -0.9238795325f, -0.9569403357f, -0.9807852804f, -0.9951847267f,
 -1.0f};
constexpr float STb[33] = {
  0.0f,           0.0980171403f,  0.1950903220f,  0.2902846773f,
  0.3826834324f,  0.4713967368f,  0.5555702330f,  0.6343932842f,
  0.7071067812f,  0.7730104534f,  0.8314696123f,  0.8819212643f,
  0.9238795325f,  0.9569403357f,  0.9807852804f,  0.9951847267f,
  1.0f,           0.9951847267f,  0.9807852804f,  0.9569403357f,
  0.9238795325f,  0.8819212643f,  0.8314696123f,  0.7730104534f,
  0.7071067812f,  0.6343932842f,  0.5555702330f,  0.4713967368f,
  0.3826834324f,  0.2902846773f,  0.1950903220f,  0.0980171403f,
  0.0f};
}

// In-register 64-point radix-2 DIT FFT, twiddles as literals. Straight-line
// only -- NO divergent control flow around re[]/im[] (R8: divergence around
// the register arrays spilled them to scratch: 2 GB of traffic).
template <bool INV>
__device__ __forceinline__ void fft64_regs(float re[64], float im[64]) {
#pragma unroll
  for (int i = 0; i < 64; ++i) {
    unsigned j = __brev((unsigned)i) >> 26;
    if ((int)j > i) {
      float tr = re[i]; re[i] = re[j]; re[j] = tr;
      float ti = im[i]; im[i] = im[j]; im[j] = ti;
    }
  }
#pragma unroll
  for (int s = 0; s < 6; ++s) {
    const int half = 1 << s;
    const int m = half << 1;
    const int tstep = 32 >> s;  // 64/m
#pragma unroll
    for (int k = 0; k < 64; k += m) {
#pragma unroll
      for (int j = 0; j < half; ++j) {
        const int ti = j * tstep;  // 0..31, compile-time
        const float wr = CT[ti];
        const float wi = INV ? STb[ti] : -STb[ti];
        const int a = k + j, b = k + j + half;
        const float tr = re[b] * wr - im[b] * wi;
        const float tii = re[b] * wi + im[b] * wr;
        re[b] = re[a] - tr; im[b] = im[a] - tii;
        re[a] = re[a] + tr; im[a] = im[a] + tii;
      }
    }
  }
}

// ---------------------------------------------------------------------------
// Branchless quadrant-swap 64x64 transpose through a HALF buffer [64][33]
// (8.4 KB -- halves the LDS that capped R7/R9 at 9 blocks/CU). Input: thread
// t holds v[j] = A[t][j]; output v[j] = A[j][t]. Round 1 moves TL+BR,
// round 2 BL+TR. Unlike R8's spilling version: no divergent loops -- LDS
// addresses are computed arithmetically (j + (t&32), t&31) and the v-half
// selection is a per-element ternary on VALUES with compile-time register
// indices (v_cndmask). Banks: (t+j)%32 patterns -> 2-way only (free).
// ---------------------------------------------------------------------------
__device__ __forceinline__ void qtrans(float v[64], float (*buf)[33],
                                       const int t) {
  const bool lo = (t < 32);
  const int cc = t & 31;        // column within the half buffer
  const int rb = t & 32;        // row-block offset for this lane's reads
#pragma unroll
  for (int j = 0; j < 32; ++j) buf[t][j] = lo ? v[j] : v[j + 32];
  __syncthreads();
#pragma unroll
  for (int j = 0; j < 32; ++j) {
    const float rd = buf[j + rb][cc];      // lo: TL[j][t]; hi: BR[j+32][t-32]
    v[j]      = lo ? rd : v[j];
    v[j + 32] = lo ? v[j + 32] : rd;
  }
  __syncthreads();
#pragma unroll
  for (int j = 0; j < 32; ++j) buf[t][j] = lo ? v[j + 32] : v[j];
  __syncthreads();
#pragma unroll
  for (int j = 0; j < 32; ++j) {
    const float rd = buf[j + (rb ^ 32)][cc];  // lo: BL[j+32][t]; hi: TR[j][t-32]
    v[j + 32] = lo ? rd : v[j + 32];
    v[j]      = lo ? v[j] : rd;
  }
  __syncthreads();
}

// Block-uniform frequency-band bounds straight from fbs (replaces k_setup's
// idx table; 2 scalar loads + trivial math).
__device__ __forceinline__ void band_from_fbs(const float* __restrict__ fbs,
                                              int c, int& s0, int& e0) {
  s0 = (int)floorf((fbs[2 * c]     + 1.0f) * 0.5f * 64.0f);
  e0 = (int)floorf((fbs[2 * c + 1] + 1.0f) * 0.5f * 64.0f);
}

// ---------------------------------------------------------------------------
// K1 v4: forward FFT2, one image per block (R7 structure: 4096 blocks --
// R9's image-pairing halved arithmetic but quartered parallelism, net loss),
// with the half-LDS branchless qtrans (8.4 KB -> 18 blocks/CU LDS cap).
// Thread t loads COLUMN t coalesced -> qtrans -> row t in regs; row FFT;
// qtrans x2 -> column t; column FFT; store straight from regs (coalesced).
// Block 0 additionally produces w1T for k_attn (k_setup folded in).
// PLANAR output per 32KB slot: active -> Fre @ +0, Fim @ +16KB; inactive
// -> |F| @ +0 (attn-only consumer).
// ---------------------------------------------------------------------------
__global__ __launch_bounds__(64) void k_fft_fwd(const float* __restrict__ x,
                                                float* __restrict__ F,
                                                const float* __restrict__ fbs,
                                                const float* __restrict__ w1,
                                                float* __restrict__ w1T) {
  __shared__ float buf[64][33];
  const int t = threadIdx.x;
  const int img = blockIdx.x;
  if (img == 0) {  // setup fold: w1T[c][k] = w1[k][c]
    for (int k = 0; k < 64; ++k) w1T[t * 64 + k] = w1[k * 64 + t];
  }
  const float* xp = x + ((size_t)img << 12);
  float re[64], im[64];
#pragma unroll
  for (int k = 0; k < 64; ++k) re[k] = xp[k * 64 + t];  // coalesced: col t
  qtrans(re, buf, t);                                   // -> row t in regs
#pragma unroll
  for (int j = 0; j < 64; ++j) im[j] = 0.0f;
  fft64_regs<false>(re, im);                            // row FFT
  qtrans(re, buf, t);
  qtrans(im, buf, t);                                   // -> column t in regs
  fft64_regs<false>(re, im);                            // column FFT
  const int b = img >> 6, i = img & 63;
  const int b_s = (b + 32) & 63, i_s = (i + 32) & 63;
  int s0, e0;
  band_from_fbs(fbs, b_s, s0, e0);
  float* Fre = F + ((size_t)img << 13);  // slot = 8192 floats
  if ((i_s >= s0) && (i_s < e0)) {  // active: planar complex (block-uniform)
    float* Fim = Fre + 4096;
#pragma unroll
    for (int j = 0; j < 64; ++j) {
      Fre[j * 64 + t] = re[j];
      Fim[j * 64 + t] = im[j];
    }
  } else {  // inactive: magnitudes only
#pragma unroll
    for (int j = 0; j < 64; ++j)
      Fre[j * 64 + t] = sqrtf(re[j] * re[j] + im[j] * im[j]);
  }
}

// ---------------------------------------------------------------------------
// K2 v5: attention. 4096 blocks x 128 threads; block = (i, row h); lane = w;
// wave wv (SGPR via readfirstlane -- threadIdx-derived addressing kills
// s_load uniformity, R5) handles c in [wv*32, wv*32+32). c-outer / k-inner,
// 64 independent acc chains (ILP=64). Contiguous active band [s0,e0)
// handled by SEGMENTED runtime-uniform loops (mag | complex+sqrt | mag).
// ---------------------------------------------------------------------------
__global__ __launch_bounds__(128) void k_attn(
    const float* __restrict__ F, const float* __restrict__ w1T,
    const float* __restrict__ b1, const float* __restrict__ w2,
    const float* __restrict__ b2, const float* __restrict__ f0,
    const float* __restrict__ theta, const float* __restrict__ sigma,
    const float* __restrict__ theta0, const float* __restrict__ fbs,
    float* __restrict__ Wc) {
  __shared__ float4 part4[64][17];  // wave1 partials; stride 17*16B: no conflict
  const int t = threadIdx.x;
  const int lane = t & 63;                                   // = w
  const int wv = __builtin_amdgcn_readfirstlane(t >> 6);     // 0/1, SGPR
  const int i = blockIdx.x >> 6;                             // attn channel
  const int h = blockIdx.x & 63;                             // row
  const int b_f = (i + 32) & 63;
  const int u_f = (h + 32) & 63;
  const int v_f = (lane + 32) & 63;
  const int pos_f = (u_f << 6) + v_f;
  int s0a, e0a;
  band_from_fbs(fbs, i, s0a, e0a);
  // this wave's c range [c0, c1), split at the active band (uniform scalars)
  const int c0 = wv << 5, c1 = c0 + 32;
  int alo = s0a < c0 ? c0 : (s0a > c1 ? c1 : s0a);
  int ahi = e0a < c0 ? c0 : (e0a > c1 ? c1 : e0a);
  if (ahi < alo) ahi = alo;  // empty band when e<=s
  float acc[64];
#pragma unroll
  for (int k = 0; k < 64; ++k) acc[k] = 0.0f;
  const float* Fb = F + ((size_t)(b_f << 6) << 13) + pos_f;
  // --- segment 1: [c0, alo) magnitudes ---
#pragma unroll 4
  for (int c = c0; c < alo; ++c) {
    const int c_f = (c + 32) & 63;
    const float mc = Fb[(size_t)c_f << 13];
    const float* wrow = w1T + (c << 6);  // uniform -> s_load
#pragma unroll
    for (int k = 0; k < 64; ++k) acc[k] = fmaf(wrow[k], mc, acc[k]);
  }
  // --- segment 2: [alo, ahi) complex + sqrt ---
#pragma unroll 2
  for (int c = alo; c < ahi; ++c) {
    const int c_f = (c + 32) & 63;
    const float* base = Fb + ((size_t)c_f << 13);
    const float xr = base[0], xi = base[4096];
    const float mc = sqrtf(xr * xr + xi * xi);
    const float* wrow = w1T + (c << 6);
#pragma unroll
    for (int k = 0; k < 64; ++k) acc[k] = fmaf(wrow[k], mc, acc[k]);
  }
  // --- segment 3: [ahi, c1) magnitudes ---
#pragma unroll 4
  for (int c = ahi; c < c1; ++c) {
    const int c_f = (c + 32) & 63;
    const float mc = Fb[(size_t)c_f << 13];
    const float* wrow = w1T + (c << 6);
#pragma unroll
    for (int k = 0; k < 64; ++k) acc[k] = fmaf(wrow[k], mc, acc[k]);
  }
  if (wv != 0) {
#pragma unroll
    for (int kk = 0; kk < 16; ++kk)
      part4[lane][kk] = make_float4(acc[4 * kk], acc[4 * kk + 1],
                                    acc[4 * kk + 2], acc[4 * kk + 3]);
  }
  __syncthreads();
  if (wv != 0) return;  // uniform exit
#pragma unroll
  for (int kk = 0; kk < 16; ++kk) {
    const float4 p = part4[lane][kk];
    acc[4 * kk] += p.x; acc[4 * kk + 1] += p.y;
    acc[4 * kk + 2] += p.z; acc[4 * kk + 3] += p.w;
  }
  float l0 = b2[0], l1 = b2[1], l2 = b2[2];
#pragma unroll
  for (int k = 0; k < 64; ++k) {
    const float hv = fmaxf(acc[k] + b1[k], 0.0f);
    l0 = fmaf(w2[k], hv, l0);  // w2 layout [S=3][HID=64]
    l1 = fmaf(w2[64 + k], hv, l1);
    l2 = fmaf(w2[128 + k], hv, l2);
  }
  float mx = fmaxf(l0, fmaxf(l1, l2));
  float e0 = expf(l0 - mx), e1 = expf(l1 - mx), e2 = expf(l2 - mx);
  float inv = 1.0f / (e0 + e1 + e2);
  float aw0 = e0 * inv, aw1 = e1 * inv, aw2 = e2 * inv;
  const float yy = -1.0f + (float)h * (2.0f / 63.0f);
  const float xx = -1.0f + (float)lane * (2.0f / 63.0f);
  const float r = sqrtf(xx * xx + yy * yy + 1e-6f);
  const float lr = logf(r);
  const float phi = atan2f(yy, xx);
  float wc = 0.0f;
  const float aws[3] = {aw0, aw1, aw2};
#pragma unroll
  for (int s = 0; s < 3; ++s) {
    const float f0v = f0[s * 64 + i];  // [S][O=1][I]
    const float sgv = sigma[s * 64 + i];
    const float thv = theta[s * 64 + i];
    const float t0v = theta0[s * 64 + i];
    const float ls = logf(sgv);
    const float d1 = lr - logf(f0v);
    const float g1 = expf(-(d1 * d1) / (2.0f * ls * ls));
    const float d2 = phi - thv;
    const float g2 = expf(-(d2 * d2) / (2.0f * t0v * t0v));
    wc = fmaf(g1 * g2, aws[s], wc);
  }
  Wc[((i << 6) + h) * 64 + lane] = wc;
}

// ---------------------------------------------------------------------------
// K3: spatial 3x3 conv (wave per output row, shuffle-assembled neighbors)
// FUSED with the inactive-image output write.
// ---------------------------------------------------------------------------
__global__ __launch_bounds__(256) void k_conv(const float* __restrict__ x,
                                              const float* __restrict__ cw,
                                              const float* __restrict__ fbs,
                                              const float* __restrict__ mixp,
                                              float* __restrict__ xsp,
                                              float* __restrict__ out) {
  __shared__ float wsm[576];
  const int t = threadIdx.x;
  for (int q = t; q < 576; q += 256) wsm[q] = cw[q];
  __syncthreads();
  const int lane = t & 63;
  const int wv = t >> 6;
  const int b = blockIdx.x >> 4;
  const int row = ((blockIdx.x & 15) << 2) | wv;
  const float* xb = x + ((size_t)b << 18);
  const int rm = row > 0 ? row - 1 : 0;  // clamped (masked in epilogue)
  const int rp = row < 63 ? row + 1 : 63;
  float P00 = 0.f, P01 = 0.f, P02 = 0.f;
  float P10 = 0.f, P11 = 0.f, P12 = 0.f;
  float P20 = 0.f, P21 = 0.f, P22 = 0.f;
#pragma unroll 4
  for (int ch = 0; ch < 64; ++ch) {
    const float* xc = xb + (ch << 12);
    const float v0 = xc[(rm << 6) + lane];
    const float v1 = xc[(row << 6) + lane];
    const float v2 = xc[(rp << 6) + lane];
    const float* wp = &wsm[ch * 9];
    P00 = fmaf(v0, wp[0], P00);
    P01 = fmaf(v0, wp[1], P01);
    P02 = fmaf(v0, wp[2], P02);
    P10 = fmaf(v1, wp[3], P10);
    P11 = fmaf(v1, wp[4], P11);
    P12 = fmaf(v1, wp[5], P12);
    P20 = fmaf(v2, wp[6], P20);
    P21 = fmaf(v2, wp[7], P21);
    P22 = fmaf(v2, wp[8], P22);
  }
  const float tmask = (row > 0) ? 1.0f : 0.0f;
  const float bmask = (row < 63) ? 1.0f : 0.0f;
  const float Ql = tmask * P00 + P10 + bmask * P20;
  const float Qm = tmask * P01 + P11 + bmask * P21;
  const float Qr = tmask * P02 + P12 + bmask * P22;
  const float fromL = __shfl_up(Ql, 1, 64);
  const float fromR = __shfl_down(Qr, 1, 64);
  float acc = Qm;
  if (lane > 0) acc += fromL;
  if (lane < 63) acc += fromR;
  xsp[((size_t)b << 12) + (row << 6) + lane] = acc;
  // Fused inactive-output epilogue (block-uniform per-i predicate).
  const int b_s = (b + 32) & 63;
  int s0, e0;
  band_from_fbs(fbs, b_s, s0, e0);
  const float val = (1.0f - mixp[0]) * acc;
  float* ob = out + ((size_t)b << 18) + (row << 6) + lane;
#pragma unroll 4
  for (int i2 = 0; i2 < 64; ++i2) {
    const int i_s = (i2 + 32) & 63;
    if (!(i_s >= s0 && i_s < e0)) ob[(size_t)i2 << 12] = val;
  }
}

// ---------------------------------------------------------------------------
// K4: ACTIVE images only (~8%): G = F*Wc(shifted)*rowmask; IFFT2; real part;
// mix with conv path. Inactive blocks exit immediately.
// ---------------------------------------------------------------------------
__global__ __launch_bounds__(64) void k_ifft_act(
    const float* __restrict__ F, const float* __restrict__ Wc,
    const float* __restrict__ xsp, const float* __restrict__ fbs,
    const float* __restrict__ mixp, float* __restrict__ out) {
  const int img = blockIdx.x;
  const int b = img >> 6, i = img & 63;
  const int b_s = (b + 32) & 63, i_s = (i + 32) & 63;
  int s0, e0;
  band_from_fbs(fbs, b_s, s0, e0);
  if (!((i_s >= s0) && (i_s < e0))) return;  // inactive: handled by k_conv
  __shared__ float buf[64][65];
  const int t = threadIdx.x;
  const float* Fre = F + ((size_t)img << 13);
  const float* Fim = Fre + 4096;
  const float* Wcp = Wc + ((size_t)i_s << 12);
  const int v_s = (t + 32) & 63;
  // stage re rows (apply Wc * row-mask during staging)
#pragma unroll
  for (int k = 0; k < 64; ++k) {
    const int u_s = (k + 32) & 63;
    const float wvv = (u_s >= s0 && u_s < e0) ? Wcp[(u_s << 6) + v_s] : 0.0f;
    buf[k][t] = Fre[k * 64 + t] * wvv;
  }
  __syncthreads();
  float re[64], im[64];
#pragma unroll
  for (int j = 0; j < 64; ++j) re[j] = buf[t][j];
  __syncthreads();
#pragma unroll
  for (int k = 0; k < 64; ++k) {
    const int u_s = (k + 32) & 63;
    const float wvv = (u_s >= s0 && u_s < e0) ? Wcp[(u_s << 6) + v_s] : 0.0f;
    buf[k][t] = Fim[k * 64 + t] * wvv;
  }
  __syncthreads();
#pragma unroll
  for (int j = 0; j < 64; ++j) im[j] = buf[t][j];
  fft64_regs<true>(re, im);  // row inverse FFTs
  // transpose (two passes)
#pragma unroll
  for (int j = 0; j < 64; ++j) buf[t][j] = re[j];
  __syncthreads();
#pragma unroll
  for (int j = 0; j < 64; ++j) re[j] = buf[j][t];
  __syncthreads();
#pragma unroll
  for (int j = 0; j < 64; ++j) buf[t][j] = im[j];
  __syncthreads();
#pragma unroll
  for (int j = 0; j < 64; ++j) im[j] = buf[j][t];
  fft64_regs<true>(re, im);  // column inverse FFTs; thread t holds column t
  const float mixv = mixp[0];
  const float sc = mixv * (1.0f / 4096.0f);
  const float om = 1.0f - mixv;
  float* op = out + ((size_t)img << 12);
  const float* xp = xsp + ((size_t)b << 12);
#pragma unroll
  for (int j = 0; j < 64; ++j)
    op[j * 64 + t] = fmaf(sc, re[j], om * xp[j * 64 + t]);
}

// ---------------------------------------------------------------------------
// Workspace layout (~131 MB):
//   [0, 128MB)        F    planar slots: active {Fre,Fim}, inactive {|F|}
//   [+128MB, +129MB)  Wc   float[64*64*64]
//   [+129MB, +130MB)  xsp  float[64*64*64]
//   [+130MB, ..)      w1T  float[64*64]   (written by k_fft_fwd block 0)
// ---------------------------------------------------------------------------
extern "C" void kernel_launch(void* const* d_in, const int* in_sizes, int n_in,
                              void* d_out, int out_size, void* d_ws, size_t ws_size,
                              hipStream_t stream) {
  const float* x      = (const float*)d_in[0];
  const float* f0     = (const float*)d_in[1];
  const float* theta  = (const float*)d_in[2];
  const float* sigma  = (const float*)d_in[3];
  const float* theta0 = (const float*)d_in[4];
  const float* fbs    = (const float*)d_in[5];
  const float* mix    = (const float*)d_in[6];
  const float* w1     = (const float*)d_in[7];
  const float* b1     = (const float*)d_in[8];
  const float* w2     = (const float*)d_in[9];
  const float* b2     = (const float*)d_in[10];
  const float* cw     = (const float*)d_in[11];
  float* out = (float*)d_out;
  char* ws = (char*)d_ws;
  float* F   = (float*)(ws);
  float* Wc  = (float*)(ws + 134217728);
  float* xsp = (float*)(ws + 134217728 + 1048576);
  float* w1T = (float*)(ws + 134217728 + 2097152);

  k_fft_fwd<<<4096, 64, 0, stream>>>(x, F, fbs, w1, w1T);
  k_attn<<<4096, 128, 0, stream>>>(F, w1T, b1, w2, b2, f0, theta, sigma, theta0, fbs, Wc);
  k_conv<<<1024, 256, 0, stream>>>(x, cw, fbs, mix, xsp, out);
  k_ifft_act<<<4096, 64, 0, stream>>>(F, Wc, xsp, fbs, mix, out);
}

// Round 11
// 260.687 us; speedup vs baseline: 3.3509x; 3.3509x over previous
//
#include <hip/hip_runtime.h>

#define PI_D 3.14159265358979323846

// ---------------------------------------------------------------------------
// Compile-time twiddle tables: CT[k]=cos(2*pi*k/64), STb[k]=sin(2*pi*k/64).
// ---------------------------------------------------------------------------
namespace {
constexpr float CT[33] = {
  1.0000000000f,  0.9951847267f,  0.9807852804f,  0.9569403357f,
  0.9238795325f,  0.8819212643f,  0.8314696123f,  0.7730104534f,
  0.7071067812f,  0.6343932842f,  0.5555702330f,  0.4713967368f,
  0.3826834324f,  0.2902846773f,  0.1950903220f,  0.0980171403f,
  0.0f,          -0.0980171403f, -0.1950903220f, -0.2902846773f,
 -0.3826834324f, -0.4713967368f, -0.5555702330f, -0.6343932842f,
 -0.7071067812f, -0.7730104534f, -0.8314696123f, -0.8819212643f,
 -0.9238795325f, -0.9569403357f, -0.9807852804f, -0.9951847267f,
 -1.0f};
constexpr float STb[33] = {
  0.0f,           0.0980171403f,  0.1950903220f,  0.2902846773f,
  0.3826834324f,  0.4713967368f,  0.5555702330f,  0.6343932842f,
  0.7071067812f,  0.7730104534f,  0.8314696123f,  0.8819212643f,
  0.9238795325f,  0.9569403357f,  0.9807852804f,  0.9951847267f,
  1.0f,           0.9951847267f,  0.9807852804f,  0.9569403357f,
  0.9238795325f,  0.8819212643f,  0.8314696123f,  0.7730104534f,
  0.7071067812f,  0.6343932842f,  0.5555702330f,  0.4713967368f,
  0.3826834324f,  0.2902846773f,  0.1950903220f,  0.0980171403f,
  0.0f};
}

// In-register 64-point radix-2 DIT FFT, twiddles as literals.
// STRAIGHT-LINE ONLY. Hard-won lesson (R8, R10): any lane-conditional
// rewriting of these 128-float register arrays -- divergent branches OR
// per-element cndmask selects -- makes the allocator spill them to scratch
// (VGPR 84-96, GBs of WRITE_SIZE, 650+ us). Only uniform control flow and
// compile-time register indices are safe.
template <bool INV>
__device__ __forceinline__ void fft64_regs(float re[64], float im[64]) {
#pragma unroll
  for (int i = 0; i < 64; ++i) {
    unsigned j = __brev((unsigned)i) >> 26;
    if ((int)j > i) {
      float tr = re[i]; re[i] = re[j]; re[j] = tr;
      float ti = im[i]; im[i] = im[j]; im[j] = ti;
    }
  }
#pragma unroll
  for (int s = 0; s < 6; ++s) {
    const int half = 1 << s;
    const int m = half << 1;
    const int tstep = 32 >> s;  // 64/m
#pragma unroll
    for (int k = 0; k < 64; k += m) {
#pragma unroll
      for (int j = 0; j < half; ++j) {
        const int ti = j * tstep;  // 0..31, compile-time
        const float wr = CT[ti];
        const float wi = INV ? STb[ti] : -STb[ti];
        const int a = k + j, b = k + j + half;
        const float tr = re[b] * wr - im[b] * wi;
        const float tii = re[b] * wi + im[b] * wr;
        re[b] = re[a] - tr; im[b] = im[a] - tii;
        re[a] = re[a] + tr; im[a] = im[a] + tii;
      }
    }
  }
}

// Block-uniform frequency-band bounds straight from fbs (2 scalar loads).
__device__ __forceinline__ void band_from_fbs(const float* __restrict__ fbs,
                                              int c, int& s0, int& e0) {
  s0 = (int)floorf((fbs[2 * c]     + 1.0f) * 0.5f * 64.0f);
  e0 = (int)floorf((fbs[2 * c + 1] + 1.0f) * 0.5f * 64.0f);
}

// ---------------------------------------------------------------------------
// K1 (R7 structure, known-good: VGPR 128, no spill, 52 us): forward FFT2,
// one image per wave-block. Full [64][65] buffer (16.6 KB), two-pass
// transposes, straight-line register FFTs. Block 0 additionally produces
// w1T for k_attn (setup fold). PLANAR output per 32KB slot: active ->
// Fre @ +0, Fim @ +16KB; inactive -> |F| @ +0 (attn-only consumer).
// The half-LDS qtrans experiments (R8/R10) both spilled -- do not retry.
// ---------------------------------------------------------------------------
__global__ __launch_bounds__(64) void k_fft_fwd(const float* __restrict__ x,
                                                float* __restrict__ F,
                                                const float* __restrict__ fbs,
                                                const float* __restrict__ w1,
                                                float* __restrict__ w1T) {
  __shared__ float buf[64][65];  // stride 65: (t+j)%32 banks -> 2-way (free)
  const int t = threadIdx.x;
  const int img = blockIdx.x;
  if (img == 0) {  // setup fold: w1T[c][k] = w1[k][c]
    for (int k = 0; k < 64; ++k) w1T[t * 64 + k] = w1[k * 64 + t];
  }
  const float* xp = x + ((size_t)img << 12);
#pragma unroll
  for (int k = 0; k < 64; ++k) buf[k][t] = xp[k * 64 + t];  // coalesced stage
  __syncthreads();
  float re[64], im[64];
#pragma unroll
  for (int j = 0; j < 64; ++j) { re[j] = buf[t][j]; im[j] = 0.0f; }  // row t
  fft64_regs<false>(re, im);
  __syncthreads();
  // transpose, two passes through the single buffer (row-private writes)
#pragma unroll
  for (int j = 0; j < 64; ++j) buf[t][j] = re[j];
  __syncthreads();
#pragma unroll
  for (int j = 0; j < 64; ++j) re[j] = buf[j][t];
  __syncthreads();
#pragma unroll
  for (int j = 0; j < 64; ++j) buf[t][j] = im[j];
  __syncthreads();
#pragma unroll
  for (int j = 0; j < 64; ++j) im[j] = buf[j][t];
  fft64_regs<false>(re, im);  // column FFT; thread t now holds column t
  const int b = img >> 6, i = img & 63;
  const int b_s = (b + 32) & 63, i_s = (i + 32) & 63;
  int s0, e0;
  band_from_fbs(fbs, b_s, s0, e0);
  float* Fre = F + ((size_t)img << 13);  // slot = 8192 floats
  if ((i_s >= s0) && (i_s < e0)) {  // active: planar complex (block-uniform)
    float* Fim = Fre + 4096;
#pragma unroll
    for (int j = 0; j < 64; ++j) {
      Fre[j * 64 + t] = re[j];
      Fim[j * 64 + t] = im[j];
    }
  } else {  // inactive: magnitudes only
#pragma unroll
    for (int j = 0; j < 64; ++j)
      Fre[j * 64 + t] = sqrtf(re[j] * re[j] + im[j] * im[j]);
  }
}

// ---------------------------------------------------------------------------
// K2 v5: attention. 4096 blocks x 128 threads; block = (i, row h); lane = w;
// wave wv (SGPR via readfirstlane -- threadIdx-derived addressing kills
// s_load uniformity, R5) handles c in [wv*32, wv*32+32). c-outer / k-inner,
// 64 independent acc chains (ILP=64). Contiguous active band [s0,e0)
// handled by SEGMENTED runtime-uniform loops (mag | complex+sqrt | mag).
// ---------------------------------------------------------------------------
__global__ __launch_bounds__(128) void k_attn(
    const float* __restrict__ F, const float* __restrict__ w1T,
    const float* __restrict__ b1, const float* __restrict__ w2,
    const float* __restrict__ b2, const float* __restrict__ f0,
    const float* __restrict__ theta, const float* __restrict__ sigma,
    const float* __restrict__ theta0, const float* __restrict__ fbs,
    float* __restrict__ Wc) {
  __shared__ float4 part4[64][17];  // wave1 partials; stride 17*16B: no conflict
  const int t = threadIdx.x;
  const int lane = t & 63;                                   // = w
  const int wv = __builtin_amdgcn_readfirstlane(t >> 6);     // 0/1, SGPR
  const int i = blockIdx.x >> 6;                             // attn channel
  const int h = blockIdx.x & 63;                             // row
  const int b_f = (i + 32) & 63;
  const int u_f = (h + 32) & 63;
  const int v_f = (lane + 32) & 63;
  const int pos_f = (u_f << 6) + v_f;
  int s0a, e0a;
  band_from_fbs(fbs, i, s0a, e0a);
  // this wave's c range [c0, c1), split at the active band (uniform scalars)
  const int c0 = wv << 5, c1 = c0 + 32;
  int alo = s0a < c0 ? c0 : (s0a > c1 ? c1 : s0a);
  int ahi = e0a < c0 ? c0 : (e0a > c1 ? c1 : e0a);
  if (ahi < alo) ahi = alo;  // empty band when e<=s
  float acc[64];
#pragma unroll
  for (int k = 0; k < 64; ++k) acc[k] = 0.0f;
  const float* Fb = F + ((size_t)(b_f << 6) << 13) + pos_f;
  // --- segment 1: [c0, alo) magnitudes ---
#pragma unroll 4
  for (int c = c0; c < alo; ++c) {
    const int c_f = (c + 32) & 63;
    const float mc = Fb[(size_t)c_f << 13];
    const float* wrow = w1T + (c << 6);  // uniform -> s_load
#pragma unroll
    for (int k = 0; k < 64; ++k) acc[k] = fmaf(wrow[k], mc, acc[k]);
  }
  // --- segment 2: [alo, ahi) complex + sqrt ---
#pragma unroll 2
  for (int c = alo; c < ahi; ++c) {
    const int c_f = (c + 32) & 63;
    const float* base = Fb + ((size_t)c_f << 13);
    const float xr = base[0], xi = base[4096];
    const float mc = sqrtf(xr * xr + xi * xi);
    const float* wrow = w1T + (c << 6);
#pragma unroll
    for (int k = 0; k < 64; ++k) acc[k] = fmaf(wrow[k], mc, acc[k]);
  }
  // --- segment 3: [ahi, c1) magnitudes ---
#pragma unroll 4
  for (int c = ahi; c < c1; ++c) {
    const int c_f = (c + 32) & 63;
    const float mc = Fb[(size_t)c_f << 13];
    const float* wrow = w1T + (c << 6);
#pragma unroll
    for (int k = 0; k < 64; ++k) acc[k] = fmaf(wrow[k], mc, acc[k]);
  }
  if (wv != 0) {
#pragma unroll
    for (int kk = 0; kk < 16; ++kk)
      part4[lane][kk] = make_float4(acc[4 * kk], acc[4 * kk + 1],
                                    acc[4 * kk + 2], acc[4 * kk + 3]);
  }
  __syncthreads();
  if (wv != 0) return;  // uniform exit
#pragma unroll
  for (int kk = 0; kk < 16; ++kk) {
    const float4 p = part4[lane][kk];
    acc[4 * kk] += p.x; acc[4 * kk + 1] += p.y;
    acc[4 * kk + 2] += p.z; acc[4 * kk + 3] += p.w;
  }
  float l0 = b2[0], l1 = b2[1], l2 = b2[2];
#pragma unroll
  for (int k = 0; k < 64; ++k) {
    const float hv = fmaxf(acc[k] + b1[k], 0.0f);
    l0 = fmaf(w2[k], hv, l0);  // w2 layout [S=3][HID=64]
    l1 = fmaf(w2[64 + k], hv, l1);
    l2 = fmaf(w2[128 + k], hv, l2);
  }
  float mx = fmaxf(l0, fmaxf(l1, l2));
  float e0 = expf(l0 - mx), e1 = expf(l1 - mx), e2 = expf(l2 - mx);
  float inv = 1.0f / (e0 + e1 + e2);
  float aw0 = e0 * inv, aw1 = e1 * inv, aw2 = e2 * inv;
  const float yy = -1.0f + (float)h * (2.0f / 63.0f);
  const float xx = -1.0f + (float)lane * (2.0f / 63.0f);
  const float r = sqrtf(xx * xx + yy * yy + 1e-6f);
  const float lr = logf(r);
  const float phi = atan2f(yy, xx);
  float wc = 0.0f;
  const float aws[3] = {aw0, aw1, aw2};
#pragma unroll
  for (int s = 0; s < 3; ++s) {
    const float f0v = f0[s * 64 + i];  // [S][O=1][I]
    const float sgv = sigma[s * 64 + i];
    const float thv = theta[s * 64 + i];
    const float t0v = theta0[s * 64 + i];
    const float ls = logf(sgv);
    const float d1 = lr - logf(f0v);
    const float g1 = expf(-(d1 * d1) / (2.0f * ls * ls));
    const float d2 = phi - thv;
    const float g2 = expf(-(d2 * d2) / (2.0f * t0v * t0v));
    wc = fmaf(g1 * g2, aws[s], wc);
  }
  Wc[((i << 6) + h) * 64 + lane] = wc;
}

// ---------------------------------------------------------------------------
// K3: spatial 3x3 conv (wave per output row, shuffle-assembled neighbors)
// FUSED with the inactive-image output write.
// ---------------------------------------------------------------------------
__global__ __launch_bounds__(256) void k_conv(const float* __restrict__ x,
                                              const float* __restrict__ cw,
                                              const float* __restrict__ fbs,
                                              const float* __restrict__ mixp,
                                              float* __restrict__ xsp,
                                              float* __restrict__ out) {
  __shared__ float wsm[576];
  const int t = threadIdx.x;
  for (int q = t; q < 576; q += 256) wsm[q] = cw[q];
  __syncthreads();
  const int lane = t & 63;
  const int wv = t >> 6;
  const int b = blockIdx.x >> 4;
  const int row = ((blockIdx.x & 15) << 2) | wv;
  const float* xb = x + ((size_t)b << 18);
  const int rm = row > 0 ? row - 1 : 0;  // clamped (masked in epilogue)
  const int rp = row < 63 ? row + 1 : 63;
  float P00 = 0.f, P01 = 0.f, P02 = 0.f;
  float P10 = 0.f, P11 = 0.f, P12 = 0.f;
  float P20 = 0.f, P21 = 0.f, P22 = 0.f;
#pragma unroll 4
  for (int ch = 0; ch < 64; ++ch) {
    const float* xc = xb + (ch << 12);
    const float v0 = xc[(rm << 6) + lane];
    const float v1 = xc[(row << 6) + lane];
    const float v2 = xc[(rp << 6) + lane];
    const float* wp = &wsm[ch * 9];
    P00 = fmaf(v0, wp[0], P00);
    P01 = fmaf(v0, wp[1], P01);
    P02 = fmaf(v0, wp[2], P02);
    P10 = fmaf(v1, wp[3], P10);
    P11 = fmaf(v1, wp[4], P11);
    P12 = fmaf(v1, wp[5], P12);
    P20 = fmaf(v2, wp[6], P20);
    P21 = fmaf(v2, wp[7], P21);
    P22 = fmaf(v2, wp[8], P22);
  }
  const float tmask = (row > 0) ? 1.0f : 0.0f;
  const float bmask = (row < 63) ? 1.0f : 0.0f;
  const float Ql = tmask * P00 + P10 + bmask * P20;
  const float Qm = tmask * P01 + P11 + bmask * P21;
  const float Qr = tmask * P02 + P12 + bmask * P22;
  const float fromL = __shfl_up(Ql, 1, 64);
  const float fromR = __shfl_down(Qr, 1, 64);
  float acc = Qm;
  if (lane > 0) acc += fromL;
  if (lane < 63) acc += fromR;
  xsp[((size_t)b << 12) + (row << 6) + lane] = acc;
  // Fused inactive-output epilogue (block-uniform per-i predicate).
  const int b_s = (b + 32) & 63;
  int s0, e0;
  band_from_fbs(fbs, b_s, s0, e0);
  const float val = (1.0f - mixp[0]) * acc;
  float* ob = out + ((size_t)b << 18) + (row << 6) + lane;
#pragma unroll 4
  for (int i2 = 0; i2 < 64; ++i2) {
    const int i_s = (i2 + 32) & 63;
    if (!(i_s >= s0 && i_s < e0)) ob[(size_t)i2 << 12] = val;
  }
}

// ---------------------------------------------------------------------------
// K4: ACTIVE images only (~8%): G = F*Wc(shifted)*rowmask; IFFT2; real part;
// mix with conv path. Inactive blocks exit immediately.
// ---------------------------------------------------------------------------
__global__ __launch_bounds__(64) void k_ifft_act(
    const float* __restrict__ F, const float* __restrict__ Wc,
    const float* __restrict__ xsp, const float* __restrict__ fbs,
    const float* __restrict__ mixp, float* __restrict__ out) {
  const int img = blockIdx.x;
  const int b = img >> 6, i = img & 63;
  const int b_s = (b + 32) & 63, i_s = (i + 32) & 63;
  int s0, e0;
  band_from_fbs(fbs, b_s, s0, e0);
  if (!((i_s >= s0) && (i_s < e0))) return;  // inactive: handled by k_conv
  __shared__ float buf[64][65];
  const int t = threadIdx.x;
  const float* Fre = F + ((size_t)img << 13);
  const float* Fim = Fre + 4096;
  const float* Wcp = Wc + ((size_t)i_s << 12);
  const int v_s = (t + 32) & 63;
  // stage re rows (apply Wc * row-mask during staging)
#pragma unroll
  for (int k = 0; k < 64; ++k) {
    const int u_s = (k + 32) & 63;
    const float wvv = (u_s >= s0 && u_s < e0) ? Wcp[(u_s << 6) + v_s] : 0.0f;
    buf[k][t] = Fre[k * 64 + t] * wvv;
  }
  __syncthreads();
  float re[64], im[64];
#pragma unroll
  for (int j = 0; j < 64; ++j) re[j] = buf[t][j];
  __syncthreads();
#pragma unroll
  for (int k = 0; k < 64; ++k) {
    const int u_s = (k + 32) & 63;
    const float wvv = (u_s >= s0 && u_s < e0) ? Wcp[(u_s << 6) + v_s] : 0.0f;
    buf[k][t] = Fim[k * 64 + t] * wvv;
  }
  __syncthreads();
#pragma unroll
  for (int j = 0; j < 64; ++j) im[j] = buf[t][j];
  fft64_regs<true>(re, im);  // row inverse FFTs
  // transpose (two passes)
#pragma unroll
  for (int j = 0; j < 64; ++j) buf[t][j] = re[j];
  __syncthreads();
#pragma unroll
  for (int j = 0; j < 64; ++j) re[j] = buf[j][t];
  __syncthreads();
#pragma unroll
  for (int j = 0; j < 64; ++j) buf[t][j] = im[j];
  __syncthreads();
#pragma unroll
  for (int j = 0; j < 64; ++j) im[j] = buf[j][t];
  fft64_regs<true>(re, im);  // column inverse FFTs; thread t holds column t
  const float mixv = mixp[0];
  const float sc = mixv * (1.0f / 4096.0f);
  const float om = 1.0f - mixv;
  float* op = out + ((size_t)img << 12);
  const float* xp = xsp + ((size_t)b << 12);
#pragma unroll
  for (int j = 0; j < 64; ++j)
    op[j * 64 + t] = fmaf(sc, re[j], om * xp[j * 64 + t]);
}

// ---------------------------------------------------------------------------
// Workspace layout (~131 MB):
//   [0, 128MB)        F    planar slots: active {Fre,Fim}, inactive {|F|}
//   [+128MB, +129MB)  Wc   float[64*64*64]
//   [+129MB, +130MB)  xsp  float[64*64*64]
//   [+130MB, ..)      w1T  float[64*64]   (written by k_fft_fwd block 0)
// ---------------------------------------------------------------------------
extern "C" void kernel_launch(void* const* d_in, const int* in_sizes, int n_in,
                              void* d_out, int out_size, void* d_ws, size_t ws_size,
                              hipStream_t stream) {
  const float* x      = (const float*)d_in[0];
  const float* f0     = (const float*)d_in[1];
  const float* theta  = (const float*)d_in[2];
  const float* sigma  = (const float*)d_in[3];
  const float* theta0 = (const float*)d_in[4];
  const float* fbs    = (const float*)d_in[5];
  const float* mix    = (const float*)d_in[6];
  const float* w1     = (const float*)d_in[7];
  const float* b1     = (const float*)d_in[8];
  const float* w2     = (const float*)d_in[9];
  const float* b2     = (const float*)d_in[10];
  const float* cw     = (const float*)d_in[11];
  float* out = (float*)d_out;
  char* ws = (char*)d_ws;
  float* F   = (float*)(ws);
  float* Wc  = (float*)(ws + 134217728);
  float* xsp = (float*)(ws + 134217728 + 1048576);
  float* w1T = (float*)(ws + 134217728 + 2097152);

  k_fft_fwd<<<4096, 64, 0, stream>>>(x, F, fbs, w1, w1T);
  k_attn<<<4096, 128, 0, stream>>>(F, w1T, b1, w2, b2, f0, theta, sigma, theta0, fbs, Wc);
  k_conv<<<1024, 256, 0, stream>>>(x, cw, fbs, mix, xsp, out);
  k_ifft_act<<<4096, 64, 0, stream>>>(F, Wc, xsp, fbs, mix, out);
}